// Round 5
// baseline (72.549 us; speedup 1.0000x reference)
//
#include <hip/hip_runtime.h>
#include <math.h>

#define NPIX 65536          // 256*256 pixels per instance
#define NGROUPS 64
#define DICE_EPS 1e-5f
#define SPLIT_T 16          // teacher: 256*16 = 4096 blocks, 16 KB f32/stream
#define SPLIT_S 16          // cross: 128*16 = 2048 blocks
#define MAX_NT 256

// ---------------------------------------------------------------------------
// Kernel 1: teacher-only streaming phase (128 MB cold). 4096 blocks; each
// block handles instance i=b/16, chunk c=b%16 (1024 float4 per stream, 4 per
// thread). All 8 loads issued back-to-back before any consumption.
// ---------------------------------------------------------------------------
__global__ __launch_bounds__(256) void teacher_stream(
    const float* __restrict__ preds_T, const float* __restrict__ gt_T,
    float* __restrict__ acc_T) {
  const int tid = threadIdx.x;
  const int i = blockIdx.x / SPLIT_T;
  const int c = blockIdx.x % SPLIT_T;
  const size_t base = (size_t)i * NPIX + (size_t)c * (NPIX / SPLIT_T);
  const float4* __restrict__ x = (const float4*)(preds_T + base);
  const float4* __restrict__ t = (const float4*)(gt_T + base);

  // burst: 8 independent loads in flight
  float4 a0 = x[tid], a1 = x[tid + 256], a2 = x[tid + 512], a3 = x[tid + 768];
  float4 b0 = t[tid], b1 = t[tid + 256], b2 = t[tid + 512], b3 = t[tid + 768];

  float inter = 0.f, xx = 0.f, tt = 0.f;
  inter += a0.x * b0.x + a0.y * b0.y + a0.z * b0.z + a0.w * b0.w;
  xx    += a0.x * a0.x + a0.y * a0.y + a0.z * a0.z + a0.w * a0.w;
  tt    += b0.x * b0.x + b0.y * b0.y + b0.z * b0.z + b0.w * b0.w;
  inter += a1.x * b1.x + a1.y * b1.y + a1.z * b1.z + a1.w * b1.w;
  xx    += a1.x * a1.x + a1.y * a1.y + a1.z * a1.z + a1.w * a1.w;
  tt    += b1.x * b1.x + b1.y * b1.y + b1.z * b1.z + b1.w * b1.w;
  inter += a2.x * b2.x + a2.y * b2.y + a2.z * b2.z + a2.w * b2.w;
  xx    += a2.x * a2.x + a2.y * a2.y + a2.z * a2.z + a2.w * a2.w;
  tt    += b2.x * b2.x + b2.y * b2.y + b2.z * b2.z + b2.w * b2.w;
  inter += a3.x * b3.x + a3.y * b3.y + a3.z * b3.z + a3.w * b3.w;
  xx    += a3.x * a3.x + a3.y * a3.y + a3.z * a3.z + a3.w * a3.w;
  tt    += b3.x * b3.x + b3.y * b3.y + b3.z * b3.z + b3.w * b3.w;

  for (int off = 32; off > 0; off >>= 1) {
    inter += __shfl_down(inter, off);
    xx    += __shfl_down(xx, off);
    tt    += __shfl_down(tt, off);
  }
  __shared__ float sm[3][4];
  const int wave = tid >> 6, lane = tid & 63;
  if (lane == 0) { sm[0][wave] = inter; sm[1][wave] = xx; sm[2][wave] = tt; }
  __syncthreads();
  if (tid == 0) {
    float I = 0.f, X = 0.f, T = 0.f;
    for (int w = 0; w < 4; ++w) { I += sm[0][w]; X += sm[1][w]; T += sm[2][w]; }
    atomicAdd(&acc_T[i * 3 + 0], I);
    atomicAdd(&acc_T[i * 3 + 1], X);
    atomicAdd(&acc_T[i * 3 + 2], T);
  }
}

// ---------------------------------------------------------------------------
// Kernel 2: finalize teacher dice + per-group argmin (first-min semantics,
// matching jnp.argmin). One block; data staged in LDS.
// ---------------------------------------------------------------------------
__global__ __launch_bounds__(256) void finalize_nms(
    const float* __restrict__ acc_T, const int* __restrict__ gt_inds_T, int nT,
    float* __restrict__ xx_T, int* __restrict__ best_idx,
    int* __restrict__ present) {
  __shared__ float iou[MAX_NT];
  __shared__ int ginds[MAX_NT];
  const int i = threadIdx.x;
  if (i < nT) {
    float I = acc_T[i * 3 + 0], X = acc_T[i * 3 + 1], T = acc_T[i * 3 + 2];
    iou[i] = 1.f - 2.f * I / (X + T + DICE_EPS);
    ginds[i] = gt_inds_T[i];
    xx_T[i] = X;
  }
  __syncthreads();
  if (i < NGROUPS) {
    float bv = INFINITY;
    int bi = 0, pres = 0;
    for (int k = 0; k < nT; ++k) {
      if (ginds[k] == i) {
        pres = 1;
        float v = iou[k];
        if (v < bv) { bv = v; bi = k; }   // strict < keeps FIRST min index
      }
    }
    best_idx[i] = bi;
    present[i] = pres;
  }
}

// ---------------------------------------------------------------------------
// Kernel 3: fused student phase — per student, BOTH sum(s*s) and
// sum(s * matched_t) in one pass over the student row (32 MB cold) plus the
// matched teacher row (16 MB, L2/L3-warm from kernel 1). Saves the 32 MB
// re-read of preds_S that the previous schedule did.
// ---------------------------------------------------------------------------
__global__ __launch_bounds__(256) void student_cross(
    const float* __restrict__ preds_S, const float* __restrict__ preds_T,
    const int* __restrict__ gt_inds_S, const int* __restrict__ best_idx,
    const int* __restrict__ present, float* __restrict__ acc_S) {
  const int s = blockIdx.x / SPLIT_S;
  const int c = blockIdx.x % SPLIT_S;
  const int g = gt_inds_S[s];
  if (!present[g]) return;   // invalid students contribute nothing
  const int j = best_idx[g];

  const int tid = threadIdx.x;
  const size_t off_s = (size_t)s * NPIX + (size_t)c * (NPIX / SPLIT_S);
  const size_t off_t = (size_t)j * NPIX + (size_t)c * (NPIX / SPLIT_S);
  const float4* __restrict__ x = (const float4*)(preds_S + off_s);
  const float4* __restrict__ t = (const float4*)(preds_T + off_t);

  float4 a0 = x[tid], a1 = x[tid + 256], a2 = x[tid + 512], a3 = x[tid + 768];
  float4 b0 = t[tid], b1 = t[tid + 256], b2 = t[tid + 512], b3 = t[tid + 768];

  float inter = 0.f, xx = 0.f;
  inter += a0.x * b0.x + a0.y * b0.y + a0.z * b0.z + a0.w * b0.w;
  xx    += a0.x * a0.x + a0.y * a0.y + a0.z * a0.z + a0.w * a0.w;
  inter += a1.x * b1.x + a1.y * b1.y + a1.z * b1.z + a1.w * b1.w;
  xx    += a1.x * a1.x + a1.y * a1.y + a1.z * a1.z + a1.w * a1.w;
  inter += a2.x * b2.x + a2.y * b2.y + a2.z * b2.z + a2.w * b2.w;
  xx    += a2.x * a2.x + a2.y * a2.y + a2.z * a2.z + a2.w * a2.w;
  inter += a3.x * b3.x + a3.y * b3.y + a3.z * b3.z + a3.w * b3.w;
  xx    += a3.x * a3.x + a3.y * a3.y + a3.z * a3.z + a3.w * a3.w;

  for (int off = 32; off > 0; off >>= 1) {
    inter += __shfl_down(inter, off);
    xx    += __shfl_down(xx, off);
  }
  __shared__ float sm[2][4];
  const int wave = tid >> 6, lane = tid & 63;
  if (lane == 0) { sm[0][wave] = inter; sm[1][wave] = xx; }
  __syncthreads();
  if (tid == 0) {
    float I = 0.f, X = 0.f;
    for (int w = 0; w < 4; ++w) { I += sm[0][w]; X += sm[1][w]; }
    atomicAdd(&acc_S[s * 2 + 0], I);
    atomicAdd(&acc_S[s * 2 + 1], X);
  }
}

// ---------------------------------------------------------------------------
// Kernel 4: final masked sum over students -> scalar (direct write).
// ---------------------------------------------------------------------------
__global__ __launch_bounds__(128) void student_final(
    const float* __restrict__ acc_S, const float* __restrict__ xx_T,
    const int* __restrict__ gt_inds_S, const int* __restrict__ best_idx,
    const int* __restrict__ present, float* __restrict__ out, int nS) {
  float v = 0.f;
  const int s = threadIdx.x;   // 128 threads, one per student
  if (s < nS) {
    const int g = gt_inds_S[s];
    if (present[g]) {
      const int j = best_idx[g];
      float I = acc_S[s * 2 + 0], X = acc_S[s * 2 + 1];
      v = 1.f - 2.f * I / (X + xx_T[j] + DICE_EPS);
    }
  }
  for (int off = 32; off > 0; off >>= 1) v += __shfl_down(v, off);
  __shared__ float p[2];
  if ((threadIdx.x & 63) == 0) p[threadIdx.x >> 6] = v;
  __syncthreads();
  if (threadIdx.x == 0) *out = p[0] + p[1];
}

extern "C" void kernel_launch(void* const* d_in, const int* in_sizes, int n_in,
                              void* d_out, int out_size, void* d_ws, size_t ws_size,
                              hipStream_t stream) {
  const float* preds_T = (const float*)d_in[0];
  const float* preds_S = (const float*)d_in[1];
  const float* gt_T    = (const float*)d_in[3];
  // d_in[2]=im_ind, d_in[4]=gt_S, d_in[5]=iter: unused by the reference
  const int* gt_inds_T = (const int*)d_in[6];
  const int* gt_inds_S = (const int*)d_in[7];
  float* out = (float*)d_out;

  const int nT = in_sizes[6];   // 256
  const int nS = in_sizes[7];   // 128

  // workspace layout (floats): acc_T[nT*3] | acc_S[nS*2] | xx_T[nT] | ints
  float* acc_T    = (float*)d_ws;
  float* acc_S    = acc_T + (size_t)nT * 3;
  float* xx_T     = acc_S + (size_t)nS * 2;
  int*   best_idx = (int*)(xx_T + nT);
  int*   present  = best_idx + NGROUPS;

  hipMemsetAsync(d_ws, 0, ((size_t)nT * 3 + (size_t)nS * 2) * sizeof(float),
                 stream);

  teacher_stream<<<nT * SPLIT_T, 256, 0, stream>>>(preds_T, gt_T, acc_T);
  finalize_nms<<<1, 256, 0, stream>>>(acc_T, gt_inds_T, nT, xx_T, best_idx,
                                      present);
  student_cross<<<nS * SPLIT_S, 256, 0, stream>>>(preds_S, preds_T, gt_inds_S,
                                                  best_idx, present, acc_S);
  student_final<<<1, 128, 0, stream>>>(acc_S, xx_T, gt_inds_S, best_idx,
                                       present, out, nS);
}

// Round 6
// 58.745 us; speedup vs baseline: 1.2350x; 1.2350x over previous
//
#include <hip/hip_runtime.h>
#include <math.h>

#define NPIX 65536          // 256*256 pixels per instance
#define NGROUPS 64
#define DICE_EPS 1e-5f
#define SPLIT_T 8           // teacher: 256*8 = 2048 blocks, 8 KB f32/stream each
#define SPLIT_S 16          // cross: 128*16 = 2048 blocks
#define MAX_NT 256

__device__ __forceinline__ void dice3(const float4& a, const float4& b,
                                      float& inter, float& xx, float& tt) {
  inter += a.x * b.x + a.y * b.y + a.z * b.z + a.w * b.w;
  xx    += a.x * a.x + a.y * a.y + a.z * a.z + a.w * a.w;
  tt    += b.x * b.x + b.y * b.y + b.z * b.z + b.w * b.w;
}

// ---------------------------------------------------------------------------
// Kernel 1: teacher streaming phase, atomic-free. 2048 blocks; block b covers
// instance i=b/8, chunk c=b%8 (2048 float4 per stream, 8 per thread, software
// pipelined 4+4). Block partials go to DISTINCT slots part_T[b*3+{0,1,2}] —
// no atomics, no memset, deterministic.
// ---------------------------------------------------------------------------
__global__ __launch_bounds__(256) void teacher_stream(
    const float* __restrict__ preds_T, const float* __restrict__ gt_T,
    float* __restrict__ part_T) {
  const int tid = threadIdx.x;
  const int b = blockIdx.x;
  const size_t base = (size_t)(b / SPLIT_T) * NPIX +
                      (size_t)(b % SPLIT_T) * (NPIX / SPLIT_T);
  const float4* __restrict__ x = (const float4*)(preds_T + base);
  const float4* __restrict__ t = (const float4*)(gt_T + base);

  float inter = 0.f, xx = 0.f, tt = 0.f;
  // batch 0 in flight
  float4 ca0 = x[tid],       ca1 = x[tid + 256],
         ca2 = x[tid + 512], ca3 = x[tid + 768];
  float4 cb0 = t[tid],       cb1 = t[tid + 256],
         cb2 = t[tid + 512], cb3 = t[tid + 768];
  // issue batch 1 before consuming batch 0
  float4 na0 = x[tid + 1024], na1 = x[tid + 1280],
         na2 = x[tid + 1536], na3 = x[tid + 1792];
  float4 nb0 = t[tid + 1024], nb1 = t[tid + 1280],
         nb2 = t[tid + 1536], nb3 = t[tid + 1792];
  dice3(ca0, cb0, inter, xx, tt);
  dice3(ca1, cb1, inter, xx, tt);
  dice3(ca2, cb2, inter, xx, tt);
  dice3(ca3, cb3, inter, xx, tt);
  dice3(na0, nb0, inter, xx, tt);
  dice3(na1, nb1, inter, xx, tt);
  dice3(na2, nb2, inter, xx, tt);
  dice3(na3, nb3, inter, xx, tt);

  for (int off = 32; off > 0; off >>= 1) {
    inter += __shfl_down(inter, off);
    xx    += __shfl_down(xx, off);
    tt    += __shfl_down(tt, off);
  }
  __shared__ float sm[3][4];
  const int wave = tid >> 6, lane = tid & 63;
  if (lane == 0) { sm[0][wave] = inter; sm[1][wave] = xx; sm[2][wave] = tt; }
  __syncthreads();
  if (tid == 0) {
    part_T[b * 3 + 0] = sm[0][0] + sm[0][1] + sm[0][2] + sm[0][3];
    part_T[b * 3 + 1] = sm[1][0] + sm[1][1] + sm[1][2] + sm[1][3];
    part_T[b * 3 + 2] = sm[2][0] + sm[2][1] + sm[2][2] + sm[2][3];
  }
}

// ---------------------------------------------------------------------------
// Kernel 2: sum the 8 chunk-partials per teacher instance, finalize dice,
// per-group argmin (first-min semantics, matching jnp.argmin). One block.
// ---------------------------------------------------------------------------
__global__ __launch_bounds__(256) void finalize_nms(
    const float* __restrict__ part_T, const int* __restrict__ gt_inds_T,
    int nT, float* __restrict__ xx_T, int* __restrict__ best_idx,
    int* __restrict__ present) {
  __shared__ float iou[MAX_NT];
  __shared__ int ginds[MAX_NT];
  const int i = threadIdx.x;
  if (i < nT) {
    float I = 0.f, X = 0.f, T = 0.f;
#pragma unroll
    for (int c = 0; c < SPLIT_T; ++c) {
      const float* p = part_T + (size_t)(i * SPLIT_T + c) * 3;
      I += p[0]; X += p[1]; T += p[2];
    }
    iou[i] = 1.f - 2.f * I / (X + T + DICE_EPS);
    ginds[i] = gt_inds_T[i];
    xx_T[i] = X;
  }
  __syncthreads();
  if (i < NGROUPS) {
    float bv = INFINITY;
    int bi = 0, pres = 0;
    for (int k = 0; k < nT; ++k) {
      if (ginds[k] == i) {
        pres = 1;
        float v = iou[k];
        if (v < bv) { bv = v; bi = k; }   // strict < keeps FIRST min index
      }
    }
    best_idx[i] = bi;
    present[i] = pres;
  }
}

// ---------------------------------------------------------------------------
// Kernel 3: fused student phase — per student, sum(s*s) and sum(s*matched_t)
// in one pass (student row cold, matched teacher row L2/L3-warm). Partials to
// distinct slots part_S[(s*SPLIT_S+c)*2+{0,1}]. Invalid students' slots are
// never read (student_final gates on `present`), so no zeroing needed.
// ---------------------------------------------------------------------------
__global__ __launch_bounds__(256) void student_cross(
    const float* __restrict__ preds_S, const float* __restrict__ preds_T,
    const int* __restrict__ gt_inds_S, const int* __restrict__ best_idx,
    const int* __restrict__ present, float* __restrict__ part_S) {
  const int s = blockIdx.x / SPLIT_S;
  const int c = blockIdx.x % SPLIT_S;
  const int g = gt_inds_S[s];
  if (!present[g]) return;
  const int j = best_idx[g];

  const int tid = threadIdx.x;
  const size_t off_s = (size_t)s * NPIX + (size_t)c * (NPIX / SPLIT_S);
  const size_t off_t = (size_t)j * NPIX + (size_t)c * (NPIX / SPLIT_S);
  const float4* __restrict__ x = (const float4*)(preds_S + off_s);
  const float4* __restrict__ t = (const float4*)(preds_T + off_t);

  float4 a0 = x[tid], a1 = x[tid + 256], a2 = x[tid + 512], a3 = x[tid + 768];
  float4 b0 = t[tid], b1 = t[tid + 256], b2 = t[tid + 512], b3 = t[tid + 768];

  float inter = 0.f, xx = 0.f;
  inter += a0.x * b0.x + a0.y * b0.y + a0.z * b0.z + a0.w * b0.w;
  xx    += a0.x * a0.x + a0.y * a0.y + a0.z * a0.z + a0.w * a0.w;
  inter += a1.x * b1.x + a1.y * b1.y + a1.z * b1.z + a1.w * b1.w;
  xx    += a1.x * a1.x + a1.y * a1.y + a1.z * a1.z + a1.w * a1.w;
  inter += a2.x * b2.x + a2.y * b2.y + a2.z * b2.z + a2.w * b2.w;
  xx    += a2.x * a2.x + a2.y * a2.y + a2.z * a2.z + a2.w * a2.w;
  inter += a3.x * b3.x + a3.y * b3.y + a3.z * b3.z + a3.w * b3.w;
  xx    += a3.x * a3.x + a3.y * a3.y + a3.z * a3.z + a3.w * a3.w;

  for (int off = 32; off > 0; off >>= 1) {
    inter += __shfl_down(inter, off);
    xx    += __shfl_down(xx, off);
  }
  __shared__ float sm[2][4];
  const int wave = tid >> 6, lane = tid & 63;
  if (lane == 0) { sm[0][wave] = inter; sm[1][wave] = xx; }
  __syncthreads();
  if (tid == 0) {
    part_S[blockIdx.x * 2 + 0] = sm[0][0] + sm[0][1] + sm[0][2] + sm[0][3];
    part_S[blockIdx.x * 2 + 1] = sm[1][0] + sm[1][1] + sm[1][2] + sm[1][3];
  }
}

// ---------------------------------------------------------------------------
// Kernel 4: sum 16 chunk-partials per student, finalize dice, masked sum ->
// scalar (direct write; d_out never needs pre-zeroing).
// ---------------------------------------------------------------------------
__global__ __launch_bounds__(128) void student_final(
    const float* __restrict__ part_S, const float* __restrict__ xx_T,
    const int* __restrict__ gt_inds_S, const int* __restrict__ best_idx,
    const int* __restrict__ present, float* __restrict__ out, int nS) {
  float v = 0.f;
  const int s = threadIdx.x;   // 128 threads, one per student
  if (s < nS) {
    const int g = gt_inds_S[s];
    if (present[g]) {
      const int j = best_idx[g];
      float I = 0.f, X = 0.f;
#pragma unroll
      for (int c = 0; c < SPLIT_S; ++c) {
        const float* p = part_S + (size_t)(s * SPLIT_S + c) * 2;
        I += p[0]; X += p[1];
      }
      v = 1.f - 2.f * I / (X + xx_T[j] + DICE_EPS);
    }
  }
  for (int off = 32; off > 0; off >>= 1) v += __shfl_down(v, off);
  __shared__ float p2[2];
  if ((threadIdx.x & 63) == 0) p2[threadIdx.x >> 6] = v;
  __syncthreads();
  if (threadIdx.x == 0) *out = p2[0] + p2[1];
}

extern "C" void kernel_launch(void* const* d_in, const int* in_sizes, int n_in,
                              void* d_out, int out_size, void* d_ws, size_t ws_size,
                              hipStream_t stream) {
  const float* preds_T = (const float*)d_in[0];
  const float* preds_S = (const float*)d_in[1];
  const float* gt_T    = (const float*)d_in[3];
  // d_in[2]=im_ind, d_in[4]=gt_S, d_in[5]=iter: unused by the reference
  const int* gt_inds_T = (const int*)d_in[6];
  const int* gt_inds_S = (const int*)d_in[7];
  float* out = (float*)d_out;

  const int nT = in_sizes[6];   // 256
  const int nS = in_sizes[7];   // 128

  // workspace layout (floats): part_T[nT*SPLIT_T*3] | part_S[nS*SPLIT_S*2] |
  // xx_T[nT] | best_idx[G] | present[G]  — all fully written before read each
  // call; no zero-init required anywhere.
  float* part_T   = (float*)d_ws;
  float* part_S   = part_T + (size_t)nT * SPLIT_T * 3;
  float* xx_T     = part_S + (size_t)nS * SPLIT_S * 2;
  int*   best_idx = (int*)(xx_T + nT);
  int*   present  = best_idx + NGROUPS;

  teacher_stream<<<nT * SPLIT_T, 256, 0, stream>>>(preds_T, gt_T, part_T);
  finalize_nms<<<1, 256, 0, stream>>>(part_T, gt_inds_T, nT, xx_T, best_idx,
                                      present);
  student_cross<<<nS * SPLIT_S, 256, 0, stream>>>(preds_S, preds_T, gt_inds_S,
                                                  best_idx, present, part_S);
  student_final<<<1, 128, 0, stream>>>(part_S, xx_T, gt_inds_S, best_idx,
                                       present, out, nS);
}